// Round 13
// baseline (309.739 us; speedup 1.0000x reference)
//
#include <hip/hip_runtime.h>
#include <hip/hip_bf16.h>

#define B_ 32
#define T_ 24
#define N_ 2048
#define D_ 64
#define K_ 32
#define H_ 16
#define NB 16

typedef __attribute__((ext_vector_type(8))) short bf16x8;
typedef __attribute__((ext_vector_type(4))) float f32x4;
typedef __attribute__((ext_vector_type(4))) int i32x4;

__device__ __forceinline__ unsigned short f2bf(float f) {
    __hip_bfloat16 h = __float2bfloat16(f);
    return *reinterpret_cast<unsigned short*>(&h);
}
__device__ __forceinline__ float bf2f(unsigned short h) {
    return __uint_as_float(((unsigned int)h) << 16);
}

// M3 bf16 [n][32 t][32 tp], zero-padded beyond 24: MFMA-A-ready, coalesced per (n,ttile)
__global__ void k_prepM(const float* __restrict__ ne, const float* __restrict__ adj,
                        unsigned short* __restrict__ M3) {
    __shared__ float s_ne[K_];
    __shared__ float s_ad[H_ * T_];
    const int n = blockIdx.x;
    const int tid = threadIdx.x;  // 64 threads
    if (tid < K_) s_ne[tid] = ne[n * K_ + tid];
    __syncthreads();
    for (int f = tid; f < H_ * T_; f += 64) {
        const int h = f / T_, t = f % T_;
        float a = 0.f;
#pragma unroll
        for (int k = 0; k < K_; ++k) a += s_ne[k] * adj[(k * H_ + h) * T_ + t];
        s_ad[f] = a;
    }
    __syncthreads();
    unsigned short* dst = M3 + (size_t)n * 1024;
    for (int idx = tid; idx < 1024; idx += 64) {
        const int t = idx >> 5, tp = idx & 31;
        float a = 0.f;
        if (t < T_ && tp < T_) {
#pragma unroll
            for (int h = 0; h < H_; ++h) a += s_ad[h * T_ + t] * s_ad[h * T_ + tp];
        }
        dst[idx] = f2bf(a);
    }
}

// Wt[bt][o][i] (bf16) = sum_k te[bt][k]*wp[k][i][o];  bias[bt][o] f32
__global__ __launch_bounds__(256) void k_prepW(const float* __restrict__ te,
                                               const float* __restrict__ wp,
                                               const float* __restrict__ bp,
                                               unsigned short* __restrict__ Wt,
                                               float* __restrict__ bias) {
    const int bt = blockIdx.x;   // 0..B*T-1
    const int tid = threadIdx.x; // 256
    __shared__ float s_te[K_];
    __shared__ float s_W[D_ * D_];  // [i][o] f32
    if (tid < K_) s_te[tid] = te[bt * K_ + tid];
    __syncthreads();
    float4 acc[4] = {};
    for (int k = 0; k < K_; ++k) {
        const float tk = s_te[k];
        const float4* row = (const float4*)(wp + (size_t)k * (D_ * D_));
#pragma unroll
        for (int i = 0; i < 4; ++i) {
            float4 v = row[tid + i * 256];
            acc[i].x += tk * v.x; acc[i].y += tk * v.y;
            acc[i].z += tk * v.z; acc[i].w += tk * v.w;
        }
    }
    float4* sW4 = (float4*)s_W;
#pragma unroll
    for (int i = 0; i < 4; ++i) sW4[tid + i * 256] = acc[i];
    if (tid < D_) {
        float a = 0.f;
#pragma unroll
        for (int k = 0; k < K_; ++k) a += s_te[k] * bp[k * D_ + tid];
        bias[bt * D_ + tid] = a;
    }
    __syncthreads();
    // transpose -> bf16: Wt[o][i]
    const int o = tid >> 2;
    const int i0 = (tid & 3) * 16;
    unsigned short* dst = Wt + (size_t)bt * (D_ * D_) + o * D_ + i0;
#pragma unroll
    for (int j = 0; j < 16; j += 4) {
        ushort4 u;
        u.x = f2bf(s_W[(i0 + j + 0) * D_ + o]);
        u.y = f2bf(s_W[(i0 + j + 1) * D_ + o]);
        u.z = f2bf(s_W[(i0 + j + 2) * D_ + o]);
        u.w = f2bf(s_W[(i0 + j + 3) * D_ + o]);
        *(ushort4*)(dst + j) = u;
    }
}

// Fused, all-MFMA. 512 threads / 8 waves, 16-node tile.
// Phase1: per wave 2 nodes: ret[n] = M3[n] @ eb[:,n,:] via 8 MFMA -> s_ret.
// Phase2: per wave 3 t's: out = leaky(ret @ Wt[bt] + bias + eb)  (R12-proven epilogue).
__global__ __launch_bounds__(512) void k_fused(const float* __restrict__ eb,
                                               const unsigned short* __restrict__ M3,
                                               const unsigned short* __restrict__ Wt,
                                               const float* __restrict__ bias,
                                               float* __restrict__ out) {
    const int b = blockIdx.y;
    const int nb = blockIdx.x * NB;
    const int tid = threadIdx.x;
    const int wave = tid >> 6, lane = tid & 63;
    const int lr = lane & 15, lh = lane >> 4;

    __shared__ unsigned short s_eb[T_ * NB * D_];   // 48KB: [tp][n][d], swz ^((n&7)<<4)^(((tp>>3)&3)<<5)
    __shared__ unsigned short s_ret[T_ * NB * D_];  // 48KB: [t][n][i],  swz ^((n&7)<<4)^(((t>>2)&3)<<5)

    // ---- stage eb slice -> s_eb ----
    {
        const float* ebb = eb + (size_t)(b * T_) * N_ * D_;
#pragma unroll
        for (int it = 0; it < 12; ++it) {
            const int f4 = it * 512 + tid;
            const int t = f4 >> 8;
            const int n = (f4 >> 4) & 15;
            const int d0 = (f4 & 15) * 4;
            const float4 v = *(const float4*)(ebb + ((size_t)t * N_ + nb + n) * D_ + d0);
            ushort4 u;
            u.x = f2bf(v.x); u.y = f2bf(v.y); u.z = f2bf(v.z); u.w = f2bf(v.w);
            const int inrow = (d0 * 2) ^ ((n & 7) << 4) ^ (((t >> 3) & 3) << 5);
            *(ushort4*)((char*)s_eb + t * 2048 + n * 128 + inrow) = u;
        }
    }
    __syncthreads();

    // ---- phase 1: MFMA mix, wave handles n = wave*2, wave*2+1 ----
    const int lhc = (lh == 3) ? 0 : lh;  // clamp k>=24 B-reads (A rows are zero there)
    for (int nn0 = 0; nn0 < 2; ++nn0) {
        const int n = wave * 2 + nn0;
        const int swn = (n & 7) << 4;
        const unsigned short* M3n = M3 + (size_t)(nb + n) * 1024;
        const bf16x8 A0 = *(const bf16x8*)(M3n + lr * 32 + lh * 8);         // rows t=lr
        const bf16x8 A1 = *(const bf16x8*)(M3n + (16 + lr) * 32 + lh * 8);  // rows t=16+lr

#pragma unroll
        for (int dt = 0; dt < 4; ++dt) {
            const char* bb = (const char*)s_eb + lhc * 8 * 2048 + n * 128 +
                             ((((dt * 16 + lr) * 2)) ^ swn ^ (lhc << 5));
            const unsigned s0 = *(const unsigned short*)(bb + 0 * 2048);
            const unsigned s1 = *(const unsigned short*)(bb + 1 * 2048);
            const unsigned s2 = *(const unsigned short*)(bb + 2 * 2048);
            const unsigned s3 = *(const unsigned short*)(bb + 3 * 2048);
            const unsigned s4 = *(const unsigned short*)(bb + 4 * 2048);
            const unsigned s5 = *(const unsigned short*)(bb + 5 * 2048);
            const unsigned s6 = *(const unsigned short*)(bb + 6 * 2048);
            const unsigned s7 = *(const unsigned short*)(bb + 7 * 2048);
            i32x4 bi;
            bi.x = (int)(s0 | (s1 << 16));
            bi.y = (int)(s2 | (s3 << 16));
            bi.z = (int)(s4 | (s5 << 16));
            bi.w = (int)(s6 | (s7 << 16));
            const bf16x8 Bf = __builtin_bit_cast(bf16x8, bi);

            f32x4 z = {0.f, 0.f, 0.f, 0.f};
            const f32x4 c0 = __builtin_amdgcn_mfma_f32_16x16x32_bf16(A0, Bf, z, 0, 0, 0);
            const f32x4 c1 = __builtin_amdgcn_mfma_f32_16x16x32_bf16(A1, Bf, z, 0, 0, 0);

            const int dby = (dt * 16 + lr) * 2;
#pragma unroll
            for (int r = 0; r < 4; ++r) {
                const int t0 = lh * 4 + r;  // (t0>>2)&3 == lh
                *(unsigned short*)((char*)s_ret + t0 * 2048 + n * 128 +
                                   (dby ^ swn ^ (lh << 5))) = f2bf(c0[r]);
            }
            if (lh < 2) {
#pragma unroll
                for (int r = 0; r < 4; ++r) {
                    const int t1 = 16 + lh * 4 + r;  // (t1>>2)&3 == lh (lh<2)
                    *(unsigned short*)((char*)s_ret + t1 * 2048 + n * 128 +
                                       (dby ^ swn ^ (lh << 5))) = f2bf(c1[r]);
                }
            }
        }
    }
    __syncthreads();

    // ---- phase 2: per wave 3 t's (R12-proven epilogue, A from s_ret) ----
    const int tb = wave * 3;
#pragma unroll
    for (int tt = 0; tt < 3; ++tt) {
        const int t = tb + tt;
        const int bt = b * T_ + t;
        const int sw2 = ((lr & 7) << 4) ^ (((t >> 2) & 3) << 5);
        const char* rbase = (const char*)s_ret + t * 2048 + lr * 128;
        const bf16x8 Af0 = *(const bf16x8*)(rbase + ((lh * 16) ^ sw2));
        const bf16x8 Af1 = *(const bf16x8*)(rbase + ((64 + lh * 16) ^ sw2));

        const unsigned short* Wb = Wt + (size_t)bt * (D_ * D_);
        f32x4 C[4] = {};
#pragma unroll
        for (int ot = 0; ot < 4; ++ot) {
            const bf16x8 B0 = *(const bf16x8*)(Wb + (ot * 16 + lr) * D_ + lh * 8);
            const bf16x8 B1 = *(const bf16x8*)(Wb + (ot * 16 + lr) * D_ + 32 + lh * 8);
            C[ot] = __builtin_amdgcn_mfma_f32_16x16x32_bf16(Af0, B0, C[ot], 0, 0, 0);
            C[ot] = __builtin_amdgcn_mfma_f32_16x16x32_bf16(Af1, B1, C[ot], 0, 0, 0);
        }
        float bv[4];
#pragma unroll
        for (int ot = 0; ot < 4; ++ot) bv[ot] = bias[bt * D_ + ot * 16 + lr];

        float* obt = out + ((size_t)bt * N_ + nb) * D_;
#pragma unroll
        for (int r = 0; r < 4; ++r) {
            const int nn = lh * 4 + r;  // C row = node
            const char* erow = (const char*)s_eb + t * 2048 + nn * 128;
            const int swn = ((nn & 7) << 4) ^ (((t >> 3) & 3) << 5);
#pragma unroll
            for (int ot = 0; ot < 4; ++ot) {
                const int o = ot * 16 + lr;  // C col
                const unsigned short eu =
                    *(const unsigned short*)(erow + ((o * 2) ^ swn));
                float v = C[ot][r] + bv[ot] + bf2f(eu);
                v = v >= 0.f ? v : 0.01f * v;
                obt[(size_t)nn * D_ + o] = v;
            }
        }
    }
}

extern "C" void kernel_launch(void* const* d_in, const int* in_sizes, int n_in,
                              void* d_out, int out_size, void* d_ws, size_t ws_size,
                              hipStream_t stream) {
    const float* eb  = (const float*)d_in[0];
    const float* ne  = (const float*)d_in[1];
    const float* te  = (const float*)d_in[2];
    const float* adj = (const float*)d_in[3];
    const float* wp  = (const float*)d_in[4];
    const float* bp  = (const float*)d_in[5];
    float* out = (float*)d_out;

    char* ws = (char*)d_ws;
    const size_t M3_bytes = (size_t)N_ * 1024 * 2;          // 4,194,304 (bf16 [n][32][32])
    const size_t Wt_bytes = (size_t)B_ * T_ * D_ * D_ * 2;  // 6,291,456
    unsigned short* M3 = (unsigned short*)ws;
    unsigned short* Wt = (unsigned short*)(ws + M3_bytes);
    float* bias        = (float*)(ws + M3_bytes + Wt_bytes);

    k_prepM<<<N_, 64, 0, stream>>>(ne, adj, M3);
    k_prepW<<<B_ * T_, 256, 0, stream>>>(te, wp, bp, Wt, bias);
    k_fused<<<dim3(N_ / NB, B_), 512, 0, stream>>>(eb, M3, Wt, bias, out);
}